// Round 1
// baseline (227.505 us; speedup 1.0000x reference)
//
#include <hip/hip_runtime.h>
#include <math.h>

// Problem constants (fixed by setup_inputs)
#define NP 8192      // pred vertices
#define NG 12000     // gt vertices
#define NFP 16384    // pred faces
#define NFG 24000    // gt faces
#define EPSF 1e-6f

// ---- workspace layout (bytes) ----
// rowmin : NP  x u64   @ 0        (65536)   packed (d2bits<<32)|idx, atomicMin
// colmin : NG  x u32   @ 65536    (48000)   f32 bits, atomicMin
// gtn    : NG*3 f32    @ 113664   (144000)  gt normal accum -> normalized in place
// pnn    : NP*3 f32    @ 257664   (98304)   pred normal accum
// nsum   : NP*3 f32    @ 355968   (98304)   laplacian neighbor sum
// deg    : NP   f32    @ 454272   (32768)   laplacian degree
// scal   : 8    f32    @ 487040            [sum_row, sum_col, pc, SX, SY, sse, lap, -]
static constexpr size_t OFF_ROWMIN = 0;
static constexpr size_t OFF_COLMIN = 65536;
static constexpr size_t OFF_GTN    = 113664;
static constexpr size_t OFF_PNN    = 257664;
static constexpr size_t OFF_NSUM   = 355968;
static constexpr size_t OFF_DEG    = 454272;
static constexpr size_t OFF_SCAL   = 487040;
#define N_ZERO 93352   // floats from OFF_GTN..end(scal)

__global__ __launch_bounds__(256) void init_kernel(unsigned long long* __restrict__ rowmin,
                                                   unsigned* __restrict__ colmin,
                                                   float* __restrict__ zero) {
    int i = blockIdx.x * 256 + threadIdx.x;
    if (i < NP) rowmin[i] = 0xFFFFFFFFFFFFFFFFULL;
    if (i < NG) colmin[i] = 0x7f800000u;            // +inf bits
    if (i < N_ZERO) zero[i] = 0.0f;
}

// scatter face normals of gt mesh
__global__ __launch_bounds__(256) void gt_face_kernel(const float* __restrict__ v,
                                                      const int* __restrict__ f,
                                                      float* __restrict__ nacc) {
    int t = blockIdx.x * 256 + threadIdx.x;
    if (t >= NFG) return;
    int i0 = f[3*t], i1 = f[3*t+1], i2 = f[3*t+2];
    float ax = v[3*i0], ay = v[3*i0+1], az = v[3*i0+2];
    float bx = v[3*i1], by = v[3*i1+1], bz = v[3*i1+2];
    float cx = v[3*i2], cy = v[3*i2+1], cz = v[3*i2+2];
    float ux = bx-ax, uy = by-ay, uz = bz-az;
    float wx = cx-ax, wy = cy-ay, wz = cz-az;
    float nx = uy*wz - uz*wy;
    float ny = uz*wx - ux*wz;
    float nz = ux*wy - uy*wx;
    atomicAdd(&nacc[3*i0+0], nx); atomicAdd(&nacc[3*i0+1], ny); atomicAdd(&nacc[3*i0+2], nz);
    atomicAdd(&nacc[3*i1+0], nx); atomicAdd(&nacc[3*i1+1], ny); atomicAdd(&nacc[3*i1+2], nz);
    atomicAdd(&nacc[3*i2+0], nx); atomicAdd(&nacc[3*i2+1], ny); atomicAdd(&nacc[3*i2+2], nz);
}

// scatter face normals + uniform-laplacian neighbor sums for pred mesh
__global__ __launch_bounds__(256) void pred_face_kernel(const float* __restrict__ v,
                                                        const int* __restrict__ f,
                                                        float* __restrict__ nacc,
                                                        float* __restrict__ nsum,
                                                        float* __restrict__ deg) {
    int t = blockIdx.x * 256 + threadIdx.x;
    if (t >= NFP) return;
    int i0 = f[3*t], i1 = f[3*t+1], i2 = f[3*t+2];
    float ax = v[3*i0], ay = v[3*i0+1], az = v[3*i0+2];
    float bx = v[3*i1], by = v[3*i1+1], bz = v[3*i1+2];
    float cx = v[3*i2], cy = v[3*i2+1], cz = v[3*i2+2];
    float ux = bx-ax, uy = by-ay, uz = bz-az;
    float wx = cx-ax, wy = cy-ay, wz = cz-az;
    float nx = uy*wz - uz*wy;
    float ny = uz*wx - ux*wz;
    float nz = ux*wy - uy*wx;
    atomicAdd(&nacc[3*i0+0], nx); atomicAdd(&nacc[3*i0+1], ny); atomicAdd(&nacc[3*i0+2], nz);
    atomicAdd(&nacc[3*i1+0], nx); atomicAdd(&nacc[3*i1+1], ny); atomicAdd(&nacc[3*i1+2], nz);
    atomicAdd(&nacc[3*i2+0], nx); atomicAdd(&nacc[3*i2+1], ny); atomicAdd(&nacc[3*i2+2], nz);
    // edges: i-lists (f0,f1,f2,f1,f2,f0) / j-lists (f1,f2,f0,f0,f1,f2)
    // => nsum[f0]+=v1+v2, nsum[f1]+=v2+v0, nsum[f2]+=v0+v1, deg[fk]+=2
    atomicAdd(&nsum[3*i0+0], bx+cx); atomicAdd(&nsum[3*i0+1], by+cy); atomicAdd(&nsum[3*i0+2], bz+cz);
    atomicAdd(&nsum[3*i1+0], cx+ax); atomicAdd(&nsum[3*i1+1], cy+ay); atomicAdd(&nsum[3*i1+2], cz+az);
    atomicAdd(&nsum[3*i2+0], ax+bx); atomicAdd(&nsum[3*i2+1], ay+by); atomicAdd(&nsum[3*i2+2], az+bz);
    atomicAdd(&deg[i0], 2.0f); atomicAdd(&deg[i1], 2.0f); atomicAdd(&deg[i2], 2.0f);
}

// normalize gt vertex normals in place
__global__ __launch_bounds__(256) void gt_norm_kernel(float* __restrict__ gtn) {
    int i = blockIdx.x * 256 + threadIdx.x;
    if (i >= NG) return;
    float x = gtn[3*i], y = gtn[3*i+1], z = gtn[3*i+2];
    float n = fmaxf(sqrtf(x*x + y*y + z*z), EPSF);
    gtn[3*i] = x/n; gtn[3*i+1] = y/n; gtn[3*i+2] = z/n;
}

// per-pred-vertex min+argmin over a 750-wide gt chunk staged in LDS
// grid: 32 pred-groups x 16 chunks = 512 blocks
#define RCH 750
__global__ __launch_bounds__(256) void row_kernel(const float* __restrict__ pred,
                                                  const float* __restrict__ gt,
                                                  unsigned long long* __restrict__ rowmin) {
    __shared__ float4 s[RCH];
    int chunk = blockIdx.x & 15;
    int pv = (blockIdx.x >> 4) * 256 + threadIdx.x;
    int gbase = chunk * RCH;
    for (int j = threadIdx.x; j < RCH; j += 256) {
        int gj = gbase + j;
        s[j] = make_float4(gt[3*gj], gt[3*gj+1], gt[3*gj+2], 0.0f);
    }
    __syncthreads();
    float px = pred[3*pv], py = pred[3*pv+1], pz = pred[3*pv+2];
    float best = 3.4e38f;
    int bidx = gbase;
    #pragma unroll 5
    for (int j = 0; j < RCH; ++j) {
        float4 q = s[j];
        float dx = px - q.x, dy = py - q.y, dz = pz - q.z;
        float d2 = fmaf(dx, dx, fmaf(dy, dy, dz*dz));
        if (d2 < best) { best = d2; bidx = gbase + j; }   // strict < keeps first index
    }
    unsigned long long key =
        ((unsigned long long)__float_as_uint(best) << 32) | (unsigned)bidx;
    atomicMin(&rowmin[pv], key);
}

// per-gt-vertex min over a 1024-wide pred chunk staged in LDS
// grid: 47 gt-groups x 8 chunks = 376 blocks
#define CCH 1024
__global__ __launch_bounds__(256) void col_kernel(const float* __restrict__ pred,
                                                  const float* __restrict__ gt,
                                                  unsigned* __restrict__ colmin) {
    __shared__ float4 s[CCH];
    int chunk = blockIdx.x & 7;
    int gv = (blockIdx.x >> 3) * 256 + threadIdx.x;
    int pbase = chunk * CCH;
    for (int j = threadIdx.x; j < CCH; j += 256) {
        int pj = pbase + j;
        s[j] = make_float4(pred[3*pj], pred[3*pj+1], pred[3*pj+2], 0.0f);
    }
    __syncthreads();
    if (gv >= NG) return;
    float gx = gt[3*gv], gy = gt[3*gv+1], gz = gt[3*gv+2];
    float best = 3.4e38f;
    #pragma unroll 4
    for (int j = 0; j < CCH; ++j) {
        float4 q = s[j];
        float dx = gx - q.x, dy = gy - q.y, dz = gz - q.z;
        float d2 = fmaf(dx, dx, fmaf(dy, dy, dz*dz));
        best = fminf(best, d2);
    }
    atomicMin(&colmin[gv], __float_as_uint(best));
}

__device__ __forceinline__ float wave_sum(float x) {
    #pragma unroll
    for (int o = 32; o > 0; o >>= 1) x += __shfl_down(x, o, 64);
    return x;
}

// per-pred-vertex finalize: distance partial, normal MSE, laplacian, focal-loss partials
__global__ __launch_bounds__(256) void fin_pred_kernel(const float* __restrict__ pred,
                                                       const float* __restrict__ relpos,
                                                       const int* __restrict__ label,
                                                       const unsigned long long* __restrict__ rowmin,
                                                       const float* __restrict__ pnn,
                                                       const float* __restrict__ gtn,
                                                       const float* __restrict__ nsum,
                                                       const float* __restrict__ deg,
                                                       float* __restrict__ scal) {
    int v = blockIdx.x * 256 + threadIdx.x;
    unsigned long long key = rowmin[v];
    float dmin = __uint_as_float((unsigned)(key >> 32));
    int nearest = (int)(unsigned)(key & 0xffffffffu);
    float px = pred[3*v], py = pred[3*v+1], pz = pred[3*v+2];

    // normal consistency term
    float ax = pnn[3*v], ay = pnn[3*v+1], az = pnn[3*v+2];
    float an = fmaxf(sqrtf(ax*ax + ay*ay + az*az), EPSF);
    float nx = ax/an - gtn[3*nearest];
    float ny = ay/an - gtn[3*nearest+1];
    float nz = az/an - gtn[3*nearest+2];
    float sse = nx*nx + ny*ny + nz*nz;

    // laplacian term
    float d = fmaxf(deg[v], 1.0f);
    float lx = nsum[3*v]/d - px;
    float ly = nsum[3*v+1]/d - py;
    float lz = nsum[3*v+2]/d - pz;
    float lapn = sqrtf(lx*lx + ly*ly + lz*lz);

    // grid-sample target (nearest, align_corners=True, zeros padding)
    float fx = rintf(px * 95.0f), fy = rintf(py * 95.0f), fz = rintf(pz * 95.0f);
    int ix = (int)fx, iy = (int)fy, iz = (int)fz;
    bool inb = (ix >= 0) & (ix < 96) & (iy >= 0) & (iy < 96) & (iz >= 0) & (iz < 96);
    int ixc = min(max(ix, 0), 95), iyc = min(max(iy, 0), 95), izc = min(max(iz, 0), 95);
    bool pos = inb && (label[(izc*96 + iyc)*96 + ixc] == 1);

    // focal partials: pos count, SX = sum_pos (1-p)^2 ln p, SY = sum_neg p^2 ln(1-p)
    float p = fminf(fmaxf(relpos[v], EPSF), 1.0f - EPSF);
    float om = 1.0f - p;
    float pcnt = 0.0f, sx = 0.0f, sy = 0.0f;
    if (pos) { pcnt = 1.0f; sx = om*om*logf(p); }
    else     { sy = p*p*logf(om); }

    float r0 = wave_sum(dmin);
    float r1 = wave_sum(sse);
    float r2 = wave_sum(lapn);
    float r3 = wave_sum(pcnt);
    float r4 = wave_sum(sx);
    float r5 = wave_sum(sy);
    if ((threadIdx.x & 63) == 0) {
        atomicAdd(&scal[0], r0);
        atomicAdd(&scal[5], r1);
        atomicAdd(&scal[6], r2);
        atomicAdd(&scal[2], r3);
        atomicAdd(&scal[3], r4);
        atomicAdd(&scal[4], r5);
    }
}

__global__ __launch_bounds__(256) void col_sum_kernel(const unsigned* __restrict__ colmin,
                                                      float* __restrict__ scal) {
    int gv = blockIdx.x * 256 + threadIdx.x;
    float val = (gv < NG) ? __uint_as_float(colmin[gv]) : 0.0f;
    float r = wave_sum(val);
    if ((threadIdx.x & 63) == 0) atomicAdd(&scal[1], r);
}

__global__ void combine_kernel(const float* __restrict__ scal, float* __restrict__ out) {
    float sum_row = scal[0], sum_col = scal[1];
    float pc = scal[2], SX = scal[3], SY = scal[4];
    float sse = scal[5], lap = scal[6];
    float tot = (float)NP;
    float alpha = (tot - pc) / (tot + EPSF);
    float spatial = (-alpha * SX - (1.0f - alpha) * SY) / (tot + EPSF);
    float distance = sum_row / (float)NP + sum_col / (float)NG;
    float normal = sse / (float)(NP * 3);
    float lapm = lap / (float)NP;
    out[0] = spatial + 1.0f * distance + 0.01f * normal + 0.1f * lapm;
}

extern "C" void kernel_launch(void* const* d_in, const int* in_sizes, int n_in,
                              void* d_out, int out_size, void* d_ws, size_t ws_size,
                              hipStream_t stream) {
    const float* pred   = (const float*)d_in[0];   // [8192,3]
    const float* relpos = (const float*)d_in[1];   // [8192]
    const float* gt     = (const float*)d_in[2];   // [12000,3]
    const int*   pfaces = (const int*)d_in[3];     // [16384,3]
    const int*   gfaces = (const int*)d_in[4];     // [24000,3]
    const int*   label  = (const int*)d_in[5];     // [1,1,96,96,96]
    float* out = (float*)d_out;

    char* ws = (char*)d_ws;
    unsigned long long* rowmin = (unsigned long long*)(ws + OFF_ROWMIN);
    unsigned*           colmin = (unsigned*)(ws + OFF_COLMIN);
    float*              gtn    = (float*)(ws + OFF_GTN);
    float*              pnn    = (float*)(ws + OFF_PNN);
    float*              nsum   = (float*)(ws + OFF_NSUM);
    float*              deg    = (float*)(ws + OFF_DEG);
    float*              scal   = (float*)(ws + OFF_SCAL);

    hipLaunchKernelGGL(init_kernel, dim3((N_ZERO + 255) / 256), dim3(256), 0, stream,
                       rowmin, colmin, (float*)(ws + OFF_GTN));
    hipLaunchKernelGGL(gt_face_kernel, dim3((NFG + 255) / 256), dim3(256), 0, stream,
                       gt, gfaces, gtn);
    hipLaunchKernelGGL(pred_face_kernel, dim3((NFP + 255) / 256), dim3(256), 0, stream,
                       pred, pfaces, pnn, nsum, deg);
    hipLaunchKernelGGL(gt_norm_kernel, dim3((NG + 255) / 256), dim3(256), 0, stream, gtn);
    hipLaunchKernelGGL(row_kernel, dim3((NP / 256) * 16), dim3(256), 0, stream,
                       pred, gt, rowmin);
    hipLaunchKernelGGL(col_kernel, dim3(((NG + 255) / 256) * 8), dim3(256), 0, stream,
                       pred, gt, colmin);
    hipLaunchKernelGGL(fin_pred_kernel, dim3(NP / 256), dim3(256), 0, stream,
                       pred, relpos, label, rowmin, pnn, gtn, nsum, deg, scal);
    hipLaunchKernelGGL(col_sum_kernel, dim3((NG + 255) / 256), dim3(256), 0, stream,
                       colmin, scal);
    hipLaunchKernelGGL(combine_kernel, dim3(1), dim3(1), 0, stream, scal, out);
}

// Round 2
// 132.788 us; speedup vs baseline: 1.7133x; 1.7133x over previous
//
#include <hip/hip_runtime.h>
#include <math.h>

// Problem constants (fixed by setup_inputs)
#define NP 8192      // pred vertices
#define NG 12000     // gt vertices
#define NFP 16384    // pred faces
#define NFG 24000    // gt faces
#define EPSF 1e-6f

// ---- workspace layout (bytes) ----
static constexpr size_t OFF_ROWMIN = 0;        // NP  x u64  packed (d2bits<<32)|idx
static constexpr size_t OFF_COLMIN = 65536;    // NG  x u32  f32 bits
static constexpr size_t OFF_GTN    = 113664;   // NG*3 f32   gt normal accum (raw)
static constexpr size_t OFF_PNN    = 257664;   // NP*3 f32   pred normal accum
static constexpr size_t OFF_NSUM   = 355968;   // NP*3 f32   laplacian neighbor sum
static constexpr size_t OFF_DEG    = 454272;   // NP   f32   laplacian degree
static constexpr size_t OFF_SCAL   = 487040;   // 8 f32 [sum_row,sum_col,pc,SX,SY,sse,lap,-]
#define N_ZERO 93352   // floats from OFF_GTN..end(scal)

__global__ __launch_bounds__(256) void init_kernel(unsigned long long* __restrict__ rowmin,
                                                   unsigned* __restrict__ colmin,
                                                   float* __restrict__ zero) {
    int i = blockIdx.x * 256 + threadIdx.x;
    if (i < NP) rowmin[i] = 0xFFFFFFFFFFFFFFFFULL;
    if (i < NG) colmin[i] = 0x7f800000u;            // +inf bits
    if (i < N_ZERO) zero[i] = 0.0f;
}

// fused face scatter: threads [0,NFG) gt faces -> gtn; [NFG, NFG+NFP) pred faces
__global__ __launch_bounds__(256) void faces_kernel(const float* __restrict__ pv,
                                                    const int* __restrict__ pf,
                                                    const float* __restrict__ gv,
                                                    const int* __restrict__ gf,
                                                    float* __restrict__ gtn,
                                                    float* __restrict__ pnn,
                                                    float* __restrict__ nsum,
                                                    float* __restrict__ deg) {
    int t = blockIdx.x * 256 + threadIdx.x;
    if (t < NFG) {
        int i0 = gf[3*t], i1 = gf[3*t+1], i2 = gf[3*t+2];
        float ax = gv[3*i0], ay = gv[3*i0+1], az = gv[3*i0+2];
        float bx = gv[3*i1], by = gv[3*i1+1], bz = gv[3*i1+2];
        float cx = gv[3*i2], cy = gv[3*i2+1], cz = gv[3*i2+2];
        float ux = bx-ax, uy = by-ay, uz = bz-az;
        float wx = cx-ax, wy = cy-ay, wz = cz-az;
        float nx = uy*wz - uz*wy, ny = uz*wx - ux*wz, nz = ux*wy - uy*wx;
        atomicAdd(&gtn[3*i0+0], nx); atomicAdd(&gtn[3*i0+1], ny); atomicAdd(&gtn[3*i0+2], nz);
        atomicAdd(&gtn[3*i1+0], nx); atomicAdd(&gtn[3*i1+1], ny); atomicAdd(&gtn[3*i1+2], nz);
        atomicAdd(&gtn[3*i2+0], nx); atomicAdd(&gtn[3*i2+1], ny); atomicAdd(&gtn[3*i2+2], nz);
    } else if (t < NFG + NFP) {
        int u = t - NFG;
        int i0 = pf[3*u], i1 = pf[3*u+1], i2 = pf[3*u+2];
        float ax = pv[3*i0], ay = pv[3*i0+1], az = pv[3*i0+2];
        float bx = pv[3*i1], by = pv[3*i1+1], bz = pv[3*i1+2];
        float cx = pv[3*i2], cy = pv[3*i2+1], cz = pv[3*i2+2];
        float ux = bx-ax, uy = by-ay, uz = bz-az;
        float wx = cx-ax, wy = cy-ay, wz = cz-az;
        float nx = uy*wz - uz*wy, ny = uz*wx - ux*wz, nz = ux*wy - uy*wx;
        atomicAdd(&pnn[3*i0+0], nx); atomicAdd(&pnn[3*i0+1], ny); atomicAdd(&pnn[3*i0+2], nz);
        atomicAdd(&pnn[3*i1+0], nx); atomicAdd(&pnn[3*i1+1], ny); atomicAdd(&pnn[3*i1+2], nz);
        atomicAdd(&pnn[3*i2+0], nx); atomicAdd(&pnn[3*i2+1], ny); atomicAdd(&pnn[3*i2+2], nz);
        atomicAdd(&nsum[3*i0+0], bx+cx); atomicAdd(&nsum[3*i0+1], by+cy); atomicAdd(&nsum[3*i0+2], bz+cz);
        atomicAdd(&nsum[3*i1+0], cx+ax); atomicAdd(&nsum[3*i1+1], cy+ay); atomicAdd(&nsum[3*i1+2], cz+az);
        atomicAdd(&nsum[3*i2+0], ax+bx); atomicAdd(&nsum[3*i2+1], ay+by); atomicAdd(&nsum[3*i2+2], az+bz);
        atomicAdd(&deg[i0], 2.0f); atomicAdd(&deg[i1], 2.0f); atomicAdd(&deg[i2], 2.0f);
    }
}

// Fused cdist: blocks [0,ROW_BLOCKS) do per-pred min+argmin; rest do per-gt min.
// Trick: d2 = |p|^2 + (|q|^2 - 2 p.q); stage (q, |q|^2) in LDS; 3 FMA per eval.
// 4-way register blocking: each thread owns 4 points (stride 256) -> one
// ds_read_b128 feeds 12 FMAs. clamp max(.,0) applied after the min (monotone).
#define ROW_GROUPS 8
#define ROW_CHUNKS 64
#define ROW_CH 188          // 64*188 = 12032 >= 12000 (padded)
#define ROW_BLOCKS (ROW_GROUPS*ROW_CHUNKS)   // 512
#define COL_GROUPS 12       // 12*1024 = 12288 >= 12000
#define COL_CHUNKS 43
#define COL_CH 192          // 43*192 = 8256 >= 8192 (padded)
#define COL_BLOCKS (COL_GROUPS*COL_CHUNKS)   // 516

__global__ __launch_bounds__(256) void cdist_kernel(const float* __restrict__ pred,
                                                    const float* __restrict__ gt,
                                                    unsigned long long* __restrict__ rowmin,
                                                    unsigned* __restrict__ colmin) {
    __shared__ float4 s[COL_CH];   // 192 >= 188
    int b = blockIdx.x;
    if (b < ROW_BLOCKS) {
        int group = b >> 6;            // 0..7
        int chunk = b & 63;            // 0..63
        int gbase = chunk * ROW_CH;
        for (int j = threadIdx.x; j < ROW_CH; j += 256) {
            int gj = gbase + j;
            if (gj < NG) {
                float x = gt[3*gj], y = gt[3*gj+1], z = gt[3*gj+2];
                s[j] = make_float4(x, y, z, fmaf(x,x, fmaf(y,y, z*z)));
            } else {
                s[j] = make_float4(0.f, 0.f, 0.f, 3.0e38f);
            }
        }
        __syncthreads();
        int pv0 = group * 1024 + threadIdx.x;
        float cx[4], cy[4], cz[4], a2[4], best[4];
        int bi[4];
        #pragma unroll
        for (int k = 0; k < 4; ++k) {
            int pv = pv0 + 256*k;
            float x = pred[3*pv], y = pred[3*pv+1], z = pred[3*pv+2];
            a2[k] = fmaf(x,x, fmaf(y,y, z*z));
            cx[k] = -2.0f*x; cy[k] = -2.0f*y; cz[k] = -2.0f*z;
            best[k] = 3.0e38f; bi[k] = 0;
        }
        #pragma unroll 4
        for (int j = 0; j < ROW_CH; ++j) {
            float4 q = s[j];
            #pragma unroll
            for (int k = 0; k < 4; ++k) {
                float t = fmaf(cx[k], q.x, fmaf(cy[k], q.y, fmaf(cz[k], q.z, q.w)));
                if (t < best[k]) { best[k] = t; bi[k] = gbase + j; }  // strict < keeps first idx
            }
        }
        #pragma unroll
        for (int k = 0; k < 4; ++k) {
            float d2 = fmaxf(a2[k] + best[k], 0.0f);
            unsigned long long key =
                ((unsigned long long)__float_as_uint(d2) << 32) | (unsigned)bi[k];
            atomicMin(&rowmin[pv0 + 256*k], key);
        }
    } else {
        int bb = b - ROW_BLOCKS;
        int group = bb / COL_CHUNKS;   // 0..11
        int chunk = bb % COL_CHUNKS;   // 0..42
        int pbase = chunk * COL_CH;
        for (int j = threadIdx.x; j < COL_CH; j += 256) {
            int pj = pbase + j;
            if (pj < NP) {
                float x = pred[3*pj], y = pred[3*pj+1], z = pred[3*pj+2];
                s[j] = make_float4(x, y, z, fmaf(x,x, fmaf(y,y, z*z)));
            } else {
                s[j] = make_float4(0.f, 0.f, 0.f, 3.0e38f);
            }
        }
        __syncthreads();
        int gv0 = group * 1024 + threadIdx.x;
        float cx[4], cy[4], cz[4], a2[4], best[4];
        #pragma unroll
        for (int k = 0; k < 4; ++k) {
            int gv = gv0 + 256*k;
            float x = 0.f, y = 0.f, z = 0.f;
            if (gv < NG) { x = gt[3*gv]; y = gt[3*gv+1]; z = gt[3*gv+2]; }
            a2[k] = fmaf(x,x, fmaf(y,y, z*z));
            cx[k] = -2.0f*x; cy[k] = -2.0f*y; cz[k] = -2.0f*z;
            best[k] = 3.0e38f;
        }
        #pragma unroll 4
        for (int j = 0; j < COL_CH; ++j) {
            float4 q = s[j];
            #pragma unroll
            for (int k = 0; k < 4; ++k) {
                float t = fmaf(cx[k], q.x, fmaf(cy[k], q.y, fmaf(cz[k], q.z, q.w)));
                best[k] = fminf(best[k], t);
            }
        }
        #pragma unroll
        for (int k = 0; k < 4; ++k) {
            int gv = gv0 + 256*k;
            if (gv < NG) {
                float d2 = fmaxf(a2[k] + best[k], 0.0f);
                atomicMin(&colmin[gv], __float_as_uint(d2));
            }
        }
    }
}

__device__ __forceinline__ float wave_sum(float x) {
    #pragma unroll
    for (int o = 32; o > 0; o >>= 1) x += __shfl_down(x, o, 64);
    return x;
}

// Fused finalize: blocks [0,32) per-pred terms; blocks [32,79) col-min sum.
#define FIN_PRED_BLOCKS 32
#define FIN_COL_BLOCKS 47
__global__ __launch_bounds__(256) void finalize_kernel(const float* __restrict__ pred,
                                                       const float* __restrict__ relpos,
                                                       const int* __restrict__ label,
                                                       const unsigned long long* __restrict__ rowmin,
                                                       const unsigned* __restrict__ colmin,
                                                       const float* __restrict__ pnn,
                                                       const float* __restrict__ gtn,
                                                       const float* __restrict__ nsum,
                                                       const float* __restrict__ deg,
                                                       float* __restrict__ scal) {
    if (blockIdx.x < FIN_PRED_BLOCKS) {
        int v = blockIdx.x * 256 + threadIdx.x;
        unsigned long long key = rowmin[v];
        float dmin = __uint_as_float((unsigned)(key >> 32));
        int nearest = (int)(unsigned)(key & 0xffffffffu);
        float px = pred[3*v], py = pred[3*v+1], pz = pred[3*v+2];

        // normal consistency (normalize both accumulators on the fly)
        float ax = pnn[3*v], ay = pnn[3*v+1], az = pnn[3*v+2];
        float an = fmaxf(sqrtf(ax*ax + ay*ay + az*az), EPSF);
        float gx = gtn[3*nearest], gy = gtn[3*nearest+1], gz = gtn[3*nearest+2];
        float gn = fmaxf(sqrtf(gx*gx + gy*gy + gz*gz), EPSF);
        float nx = ax/an - gx/gn, ny = ay/an - gy/gn, nz = az/an - gz/gn;
        float sse = nx*nx + ny*ny + nz*nz;

        // laplacian
        float d = fmaxf(deg[v], 1.0f);
        float lx = nsum[3*v]/d - px, ly = nsum[3*v+1]/d - py, lz = nsum[3*v+2]/d - pz;
        float lapn = sqrtf(lx*lx + ly*ly + lz*lz);

        // grid-sample target (nearest, align_corners=True, zeros padding)
        int ix = (int)rintf(px * 95.0f), iy = (int)rintf(py * 95.0f), iz = (int)rintf(pz * 95.0f);
        bool inb = (ix >= 0) & (ix < 96) & (iy >= 0) & (iy < 96) & (iz >= 0) & (iz < 96);
        int ixc = min(max(ix, 0), 95), iyc = min(max(iy, 0), 95), izc = min(max(iz, 0), 95);
        bool pos = inb && (label[(izc*96 + iyc)*96 + ixc] == 1);

        float p = fminf(fmaxf(relpos[v], EPSF), 1.0f - EPSF);
        float om = 1.0f - p;
        float pcnt = 0.0f, sx = 0.0f, sy = 0.0f;
        if (pos) { pcnt = 1.0f; sx = om*om*logf(p); }
        else     { sy = p*p*logf(om); }

        float r0 = wave_sum(dmin);
        float r1 = wave_sum(sse);
        float r2 = wave_sum(lapn);
        float r3 = wave_sum(pcnt);
        float r4 = wave_sum(sx);
        float r5 = wave_sum(sy);
        if ((threadIdx.x & 63) == 0) {
            atomicAdd(&scal[0], r0);
            atomicAdd(&scal[5], r1);
            atomicAdd(&scal[6], r2);
            atomicAdd(&scal[2], r3);
            atomicAdd(&scal[3], r4);
            atomicAdd(&scal[4], r5);
        }
    } else {
        int gv = (blockIdx.x - FIN_PRED_BLOCKS) * 256 + threadIdx.x;
        float val = (gv < NG) ? __uint_as_float(colmin[gv]) : 0.0f;
        float r = wave_sum(val);
        if ((threadIdx.x & 63) == 0) atomicAdd(&scal[1], r);
    }
}

__global__ void combine_kernel(const float* __restrict__ scal, float* __restrict__ out) {
    float sum_row = scal[0], sum_col = scal[1];
    float pc = scal[2], SX = scal[3], SY = scal[4];
    float sse = scal[5], lap = scal[6];
    float tot = (float)NP;
    float alpha = (tot - pc) / (tot + EPSF);
    float spatial = (-alpha * SX - (1.0f - alpha) * SY) / (tot + EPSF);
    float distance = sum_row / (float)NP + sum_col / (float)NG;
    float normal = sse / (float)(NP * 3);
    float lapm = lap / (float)NP;
    out[0] = spatial + 1.0f * distance + 0.01f * normal + 0.1f * lapm;
}

extern "C" void kernel_launch(void* const* d_in, const int* in_sizes, int n_in,
                              void* d_out, int out_size, void* d_ws, size_t ws_size,
                              hipStream_t stream) {
    const float* pred   = (const float*)d_in[0];   // [8192,3]
    const float* relpos = (const float*)d_in[1];   // [8192]
    const float* gt     = (const float*)d_in[2];   // [12000,3]
    const int*   pfaces = (const int*)d_in[3];     // [16384,3]
    const int*   gfaces = (const int*)d_in[4];     // [24000,3]
    const int*   label  = (const int*)d_in[5];     // [1,1,96,96,96]
    float* out = (float*)d_out;

    char* ws = (char*)d_ws;
    unsigned long long* rowmin = (unsigned long long*)(ws + OFF_ROWMIN);
    unsigned*           colmin = (unsigned*)(ws + OFF_COLMIN);
    float*              gtn    = (float*)(ws + OFF_GTN);
    float*              pnn    = (float*)(ws + OFF_PNN);
    float*              nsum   = (float*)(ws + OFF_NSUM);
    float*              deg    = (float*)(ws + OFF_DEG);
    float*              scal   = (float*)(ws + OFF_SCAL);

    hipLaunchKernelGGL(init_kernel, dim3((N_ZERO + 255) / 256), dim3(256), 0, stream,
                       rowmin, colmin, gtn);
    hipLaunchKernelGGL(faces_kernel, dim3((NFG + NFP + 255) / 256), dim3(256), 0, stream,
                       pred, pfaces, gt, gfaces, gtn, pnn, nsum, deg);
    hipLaunchKernelGGL(cdist_kernel, dim3(ROW_BLOCKS + COL_BLOCKS), dim3(256), 0, stream,
                       pred, gt, rowmin, colmin);
    hipLaunchKernelGGL(finalize_kernel, dim3(FIN_PRED_BLOCKS + FIN_COL_BLOCKS), dim3(256), 0, stream,
                       pred, relpos, label, rowmin, colmin, pnn, gtn, nsum, deg, scal);
    hipLaunchKernelGGL(combine_kernel, dim3(1), dim3(1), 0, stream, scal, out);
}

// Round 3
// 120.197 us; speedup vs baseline: 1.8928x; 1.1048x over previous
//
#include <hip/hip_runtime.h>
#include <math.h>

// Problem constants (fixed by setup_inputs)
#define NP 8192      // pred vertices
#define NG 12000     // gt vertices
#define NFP 16384    // pred faces
#define NFG 24000    // gt faces
#define EPSF 1e-6f

// ---- workspace layout (bytes) ----
static constexpr size_t OFF_ROWMIN = 0;        // NP  x u64  packed (d2bits<<32)|idx
static constexpr size_t OFF_COLMIN = 65536;    // NG  x u32  f32 bits
static constexpr size_t OFF_GTN    = 113664;   // NG*3 f32   gt normal accum (raw)
static constexpr size_t OFF_PNN    = 257664;   // NP*3 f32   pred normal accum
static constexpr size_t OFF_NSUM   = 355968;   // NP*3 f32   laplacian neighbor sum
static constexpr size_t OFF_DEG    = 454272;   // NP   f32   laplacian degree
static constexpr size_t OFF_SCAL   = 487040;   // 8 f32 [sum_row,sum_col,pc,SX,SY,sse,lap,ticket]
#define N_ZERO 93352   // floats from OFF_GTN..end(scal) — covers scal[0..7] incl. ticket

__global__ __launch_bounds__(256) void init_kernel(unsigned long long* __restrict__ rowmin,
                                                   unsigned* __restrict__ colmin,
                                                   float* __restrict__ zero) {
    int i = blockIdx.x * 256 + threadIdx.x;
    if (i < NP) rowmin[i] = 0xFFFFFFFFFFFFFFFFULL;
    if (i < NG) colmin[i] = 0x7f800000u;            // +inf bits
    if (i < N_ZERO) zero[i] = 0.0f;
}

// Fused cdist + face-scatter dispatch.
// Blocks [0, ROW_BLOCKS)                : per-pred min+argmin over a gt chunk
// Blocks [ROW_BLOCKS, ROW+COL)          : per-gt min over a pred chunk
// Blocks [ROW+COL, ROW+COL+FACE_BLOCKS) : face-normal / laplacian scatter
// cdist trick: d2 = |p|^2 + (|q|^2 - 2 p.q); stage (q,|q|^2) in LDS -> 3 FMA/eval.
// 4-way register blocking: one ds_read_b128 feeds 4 points. max(.,0) after min
// is valid (monotone, |p|^2 constant per row).
#define ROW_GROUPS 8
#define ROW_CHUNKS 64
#define ROW_CH 188          // 64*188 = 12032 >= 12000 (padded)
#define ROW_BLOCKS (ROW_GROUPS*ROW_CHUNKS)   // 512
#define COL_GROUPS 12       // 12*1024 = 12288 >= 12000
#define COL_CHUNKS 43
#define COL_CH 192          // 43*192 = 8256 >= 8192 (padded)
#define COL_BLOCKS (COL_GROUPS*COL_CHUNKS)   // 516
#define CD_BLOCKS (ROW_BLOCKS + COL_BLOCKS)  // 1028
#define FACE_BLOCKS ((NFG + NFP + 255) / 256) // 158

__global__ __launch_bounds__(256) void mega_kernel(const float* __restrict__ pred,
                                                   const int* __restrict__ pf,
                                                   const float* __restrict__ gt,
                                                   const int* __restrict__ gf,
                                                   unsigned long long* __restrict__ rowmin,
                                                   unsigned* __restrict__ colmin,
                                                   float* __restrict__ gtn,
                                                   float* __restrict__ pnn,
                                                   float* __restrict__ nsum,
                                                   float* __restrict__ deg) {
    __shared__ float4 s[COL_CH];   // 192 >= 188
    int b = blockIdx.x;
    if (b < ROW_BLOCKS) {
        int group = b >> 6;            // 0..7
        int chunk = b & 63;            // 0..63
        int gbase = chunk * ROW_CH;
        for (int j = threadIdx.x; j < ROW_CH; j += 256) {
            int gj = gbase + j;
            if (gj < NG) {
                float x = gt[3*gj], y = gt[3*gj+1], z = gt[3*gj+2];
                s[j] = make_float4(x, y, z, fmaf(x,x, fmaf(y,y, z*z)));
            } else {
                s[j] = make_float4(0.f, 0.f, 0.f, 3.0e38f);
            }
        }
        __syncthreads();
        int pv0 = group * 1024 + threadIdx.x;
        float cx[4], cy[4], cz[4], a2[4], best[4];
        int bi[4];
        #pragma unroll
        for (int k = 0; k < 4; ++k) {
            int pv = pv0 + 256*k;
            float x = pred[3*pv], y = pred[3*pv+1], z = pred[3*pv+2];
            a2[k] = fmaf(x,x, fmaf(y,y, z*z));
            cx[k] = -2.0f*x; cy[k] = -2.0f*y; cz[k] = -2.0f*z;
            best[k] = 3.0e38f; bi[k] = 0;
        }
        #pragma unroll 4
        for (int j = 0; j < ROW_CH; ++j) {
            float4 q = s[j];
            #pragma unroll
            for (int k = 0; k < 4; ++k) {
                float t = fmaf(cx[k], q.x, fmaf(cy[k], q.y, fmaf(cz[k], q.z, q.w)));
                if (t < best[k]) { best[k] = t; bi[k] = gbase + j; }  // strict < keeps first idx
            }
        }
        #pragma unroll
        for (int k = 0; k < 4; ++k) {
            float d2 = fmaxf(a2[k] + best[k], 0.0f);
            unsigned long long key =
                ((unsigned long long)__float_as_uint(d2) << 32) | (unsigned)bi[k];
            atomicMin(&rowmin[pv0 + 256*k], key);
        }
    } else if (b < CD_BLOCKS) {
        int bb = b - ROW_BLOCKS;
        int group = bb / COL_CHUNKS;   // 0..11
        int chunk = bb % COL_CHUNKS;   // 0..42
        int pbase = chunk * COL_CH;
        for (int j = threadIdx.x; j < COL_CH; j += 256) {
            int pj = pbase + j;
            if (pj < NP) {
                float x = pred[3*pj], y = pred[3*pj+1], z = pred[3*pj+2];
                s[j] = make_float4(x, y, z, fmaf(x,x, fmaf(y,y, z*z)));
            } else {
                s[j] = make_float4(0.f, 0.f, 0.f, 3.0e38f);
            }
        }
        __syncthreads();
        int gv0 = group * 1024 + threadIdx.x;
        float cx[4], cy[4], cz[4], a2[4], best[4];
        #pragma unroll
        for (int k = 0; k < 4; ++k) {
            int gv = gv0 + 256*k;
            float x = 0.f, y = 0.f, z = 0.f;
            if (gv < NG) { x = gt[3*gv]; y = gt[3*gv+1]; z = gt[3*gv+2]; }
            a2[k] = fmaf(x,x, fmaf(y,y, z*z));
            cx[k] = -2.0f*x; cy[k] = -2.0f*y; cz[k] = -2.0f*z;
            best[k] = 3.0e38f;
        }
        #pragma unroll 4
        for (int j = 0; j < COL_CH; ++j) {
            float4 q = s[j];
            #pragma unroll
            for (int k = 0; k < 4; ++k) {
                float t = fmaf(cx[k], q.x, fmaf(cy[k], q.y, fmaf(cz[k], q.z, q.w)));
                best[k] = fminf(best[k], t);
            }
        }
        #pragma unroll
        for (int k = 0; k < 4; ++k) {
            int gv = gv0 + 256*k;
            if (gv < NG) {
                float d2 = fmaxf(a2[k] + best[k], 0.0f);
                atomicMin(&colmin[gv], __float_as_uint(d2));
            }
        }
    } else {
        // face scatter: gt faces then pred faces
        int t = (b - CD_BLOCKS) * 256 + threadIdx.x;
        if (t < NFG) {
            int i0 = gf[3*t], i1 = gf[3*t+1], i2 = gf[3*t+2];
            float ax = gt[3*i0], ay = gt[3*i0+1], az = gt[3*i0+2];
            float bx = gt[3*i1], by = gt[3*i1+1], bz = gt[3*i1+2];
            float cx = gt[3*i2], cy = gt[3*i2+1], cz = gt[3*i2+2];
            float ux = bx-ax, uy = by-ay, uz = bz-az;
            float wx = cx-ax, wy = cy-ay, wz = cz-az;
            float nx = uy*wz - uz*wy, ny = uz*wx - ux*wz, nz = ux*wy - uy*wx;
            atomicAdd(&gtn[3*i0+0], nx); atomicAdd(&gtn[3*i0+1], ny); atomicAdd(&gtn[3*i0+2], nz);
            atomicAdd(&gtn[3*i1+0], nx); atomicAdd(&gtn[3*i1+1], ny); atomicAdd(&gtn[3*i1+2], nz);
            atomicAdd(&gtn[3*i2+0], nx); atomicAdd(&gtn[3*i2+1], ny); atomicAdd(&gtn[3*i2+2], nz);
        } else if (t < NFG + NFP) {
            int u = t - NFG;
            int i0 = pf[3*u], i1 = pf[3*u+1], i2 = pf[3*u+2];
            float ax = pred[3*i0], ay = pred[3*i0+1], az = pred[3*i0+2];
            float bx = pred[3*i1], by = pred[3*i1+1], bz = pred[3*i1+2];
            float cx = pred[3*i2], cy = pred[3*i2+1], cz = pred[3*i2+2];
            float ux = bx-ax, uy = by-ay, uz = bz-az;
            float wx = cx-ax, wy = cy-ay, wz = cz-az;
            float nx = uy*wz - uz*wy, ny = uz*wx - ux*wz, nz = ux*wy - uy*wx;
            atomicAdd(&pnn[3*i0+0], nx); atomicAdd(&pnn[3*i0+1], ny); atomicAdd(&pnn[3*i0+2], nz);
            atomicAdd(&pnn[3*i1+0], nx); atomicAdd(&pnn[3*i1+1], ny); atomicAdd(&pnn[3*i1+2], nz);
            atomicAdd(&pnn[3*i2+0], nx); atomicAdd(&pnn[3*i2+1], ny); atomicAdd(&pnn[3*i2+2], nz);
            atomicAdd(&nsum[3*i0+0], bx+cx); atomicAdd(&nsum[3*i0+1], by+cy); atomicAdd(&nsum[3*i0+2], bz+cz);
            atomicAdd(&nsum[3*i1+0], cx+ax); atomicAdd(&nsum[3*i1+1], cy+ay); atomicAdd(&nsum[3*i1+2], cz+az);
            atomicAdd(&nsum[3*i2+0], ax+bx); atomicAdd(&nsum[3*i2+1], ay+by); atomicAdd(&nsum[3*i2+2], az+bz);
            atomicAdd(&deg[i0], 2.0f); atomicAdd(&deg[i1], 2.0f); atomicAdd(&deg[i2], 2.0f);
        }
    }
}

__device__ __forceinline__ float wave_sum(float x) {
    #pragma unroll
    for (int o = 32; o > 0; o >>= 1) x += __shfl_down(x, o, 64);
    return x;
}

// Fused finalize: blocks [0,32) per-pred terms; [32,79) col-min sum;
// last block (atomic ticket) computes the final scalar and writes d_out.
#define FIN_PRED_BLOCKS 32
#define FIN_COL_BLOCKS 47
#define FIN_TOTAL (FIN_PRED_BLOCKS + FIN_COL_BLOCKS)
__global__ __launch_bounds__(256) void finalize_kernel(const float* __restrict__ pred,
                                                       const float* __restrict__ relpos,
                                                       const int* __restrict__ label,
                                                       const unsigned long long* __restrict__ rowmin,
                                                       const unsigned* __restrict__ colmin,
                                                       const float* __restrict__ pnn,
                                                       const float* __restrict__ gtn,
                                                       const float* __restrict__ nsum,
                                                       const float* __restrict__ deg,
                                                       float* __restrict__ scal,
                                                       unsigned* __restrict__ ticket,
                                                       float* __restrict__ out) {
    if (blockIdx.x < FIN_PRED_BLOCKS) {
        int v = blockIdx.x * 256 + threadIdx.x;
        unsigned long long key = rowmin[v];
        float dmin = __uint_as_float((unsigned)(key >> 32));
        int nearest = (int)(unsigned)(key & 0xffffffffu);
        float px = pred[3*v], py = pred[3*v+1], pz = pred[3*v+2];

        // normal consistency (normalize both accumulators on the fly)
        float ax = pnn[3*v], ay = pnn[3*v+1], az = pnn[3*v+2];
        float an = fmaxf(sqrtf(ax*ax + ay*ay + az*az), EPSF);
        float gx = gtn[3*nearest], gy = gtn[3*nearest+1], gz = gtn[3*nearest+2];
        float gn = fmaxf(sqrtf(gx*gx + gy*gy + gz*gz), EPSF);
        float nx = ax/an - gx/gn, ny = ay/an - gy/gn, nz = az/an - gz/gn;
        float sse = nx*nx + ny*ny + nz*nz;

        // laplacian
        float d = fmaxf(deg[v], 1.0f);
        float lx = nsum[3*v]/d - px, ly = nsum[3*v+1]/d - py, lz = nsum[3*v+2]/d - pz;
        float lapn = sqrtf(lx*lx + ly*ly + lz*lz);

        // grid-sample target (nearest, align_corners=True, zeros padding)
        int ix = (int)rintf(px * 95.0f), iy = (int)rintf(py * 95.0f), iz = (int)rintf(pz * 95.0f);
        bool inb = (ix >= 0) & (ix < 96) & (iy >= 0) & (iy < 96) & (iz >= 0) & (iz < 96);
        int ixc = min(max(ix, 0), 95), iyc = min(max(iy, 0), 95), izc = min(max(iz, 0), 95);
        bool pos = inb && (label[(izc*96 + iyc)*96 + ixc] == 1);

        float p = fminf(fmaxf(relpos[v], EPSF), 1.0f - EPSF);
        float om = 1.0f - p;
        float pcnt = 0.0f, sx = 0.0f, sy = 0.0f;
        if (pos) { pcnt = 1.0f; sx = om*om*logf(p); }
        else     { sy = p*p*logf(om); }

        float r0 = wave_sum(dmin);
        float r1 = wave_sum(sse);
        float r2 = wave_sum(lapn);
        float r3 = wave_sum(pcnt);
        float r4 = wave_sum(sx);
        float r5 = wave_sum(sy);
        if ((threadIdx.x & 63) == 0) {
            atomicAdd(&scal[0], r0);
            atomicAdd(&scal[5], r1);
            atomicAdd(&scal[6], r2);
            atomicAdd(&scal[2], r3);
            atomicAdd(&scal[3], r4);
            atomicAdd(&scal[4], r5);
        }
    } else {
        int gv = (blockIdx.x - FIN_PRED_BLOCKS) * 256 + threadIdx.x;
        float val = (gv < NG) ? __uint_as_float(colmin[gv]) : 0.0f;
        float r = wave_sum(val);
        if ((threadIdx.x & 63) == 0) atomicAdd(&scal[1], r);
    }

    // last-block combine (device-scope atomics; fence orders our adds before ticket)
    __threadfence();
    __shared__ int is_last;
    if (threadIdx.x == 0) {
        unsigned t = atomicAdd(ticket, 1u);
        is_last = (t == FIN_TOTAL - 1) ? 1 : 0;
    }
    __syncthreads();
    if (is_last && threadIdx.x == 0) {
        // atomic reads (add 0) guarantee L2-coherent values
        float sum_row = atomicAdd(&scal[0], 0.0f);
        float sum_col = atomicAdd(&scal[1], 0.0f);
        float pc      = atomicAdd(&scal[2], 0.0f);
        float SX      = atomicAdd(&scal[3], 0.0f);
        float SY      = atomicAdd(&scal[4], 0.0f);
        float sse     = atomicAdd(&scal[5], 0.0f);
        float lap     = atomicAdd(&scal[6], 0.0f);
        float tot = (float)NP;
        float alpha = (tot - pc) / (tot + EPSF);
        float spatial = (-alpha * SX - (1.0f - alpha) * SY) / (tot + EPSF);
        float distance = sum_row / (float)NP + sum_col / (float)NG;
        float normal = sse / (float)(NP * 3);
        float lapm = lap / (float)NP;
        out[0] = spatial + 1.0f * distance + 0.01f * normal + 0.1f * lapm;
    }
}

extern "C" void kernel_launch(void* const* d_in, const int* in_sizes, int n_in,
                              void* d_out, int out_size, void* d_ws, size_t ws_size,
                              hipStream_t stream) {
    const float* pred   = (const float*)d_in[0];   // [8192,3]
    const float* relpos = (const float*)d_in[1];   // [8192]
    const float* gt     = (const float*)d_in[2];   // [12000,3]
    const int*   pfaces = (const int*)d_in[3];     // [16384,3]
    const int*   gfaces = (const int*)d_in[4];     // [24000,3]
    const int*   label  = (const int*)d_in[5];     // [1,1,96,96,96]
    float* out = (float*)d_out;

    char* ws = (char*)d_ws;
    unsigned long long* rowmin = (unsigned long long*)(ws + OFF_ROWMIN);
    unsigned*           colmin = (unsigned*)(ws + OFF_COLMIN);
    float*              gtn    = (float*)(ws + OFF_GTN);
    float*              pnn    = (float*)(ws + OFF_PNN);
    float*              nsum   = (float*)(ws + OFF_NSUM);
    float*              deg    = (float*)(ws + OFF_DEG);
    float*              scal   = (float*)(ws + OFF_SCAL);
    unsigned*           ticket = (unsigned*)(ws + OFF_SCAL + 7*sizeof(float));

    hipLaunchKernelGGL(init_kernel, dim3((N_ZERO + 255) / 256), dim3(256), 0, stream,
                       rowmin, colmin, gtn);
    hipLaunchKernelGGL(mega_kernel, dim3(CD_BLOCKS + FACE_BLOCKS), dim3(256), 0, stream,
                       pred, pfaces, gt, gfaces, rowmin, colmin, gtn, pnn, nsum, deg);
    hipLaunchKernelGGL(finalize_kernel, dim3(FIN_TOTAL), dim3(256), 0, stream,
                       pred, relpos, label, rowmin, colmin, pnn, gtn, nsum, deg,
                       scal, ticket, out);
}